// Round 16
// baseline (538.700 us; speedup 1.0000x reference)
//
#include <hip/hip_runtime.h>
#include <cstdint>
#include <cstddef>

#define EDIM  512
#define NROWS 16384
#define NE    8192
#define XQSZ  (NROWS * EDIM)   // 8388608
#define NTILE 64               // 8192 codes / 128 per tile
#define K3    1536             // 3-block split: [hi, mid, lo]

// workspace byte offsets
#define OFF_PART  0                          // 2048 doubles
#define OFF_Z     16384
#define OFF_C2    81920
#define OFF_KEYS  114688
#define OFF_TMIN  245760                     // NROWS*NTILE*4 = 4 MB
#define OFF_CNT   4440064
#define OFF_LIST  4441088                    // NROWS*NTILE*4 = 4 MB
#define OFF_XE    8635392                    // NROWS*K3*2 = 48 MB
#define OFF_WE    58967040                   // NE*K3*2 = 24 MB (end ~84 MB)

// k_prep grid regions
#define PREP_RN   3072                       // rownorm: 2 rows/wave, 8 rows/block
#define PREP_SX   (PREP_RN + 8192)           // x split
#define PREP_SW   (PREP_SX + 4096)           // W split
#define PREP_KEYS (PREP_SW + 64)             // keys init
#define PREP_ALL  (PREP_KEYS + 1)            // + cnt zero

typedef __attribute__((ext_vector_type(8)))  short          short8;
typedef __attribute__((ext_vector_type(16))) float          f32x16;
typedef __attribute__((ext_vector_type(4)))  unsigned short u16x4;

// ---------------- bf16 split helpers ----------------
__device__ __forceinline__ unsigned short f2bf(float f) {
    unsigned u = __float_as_uint(f);
    return (unsigned short)((u + 0x7FFFu + ((u >> 16) & 1u)) >> 16);
}
__device__ __forceinline__ float bf2f(unsigned short h) {
    return __uint_as_float(((unsigned)h) << 16);
}

__device__ __forceinline__ void split_group(const float* __restrict__ in,
        unsigned short* __restrict__ outp, int e) {
    int row = e >> 7;               // 128 float4-groups per row
    int d0  = (e & 127) << 2;
    float4 v = *(const float4*)(in + (size_t)row * EDIM + d0);
    float vv[4] = {v.x, v.y, v.z, v.w};
    u16x4 H, M, L;
#pragma unroll
    for (int i = 0; i < 4; ++i) {
        float f = vv[i];
        unsigned short h = f2bf(f);
        float r1 = f - bf2f(h);          // exact
        unsigned short m = f2bf(r1);
        float r2 = r1 - bf2f(m);         // exact
        L[i] = f2bf(r2); H[i] = h; M[i] = m;
    }
    unsigned short* o = outp + (size_t)row * K3 + d0;
    *(u16x4*)(o) = H; *(u16x4*)(o + EDIM) = M; *(u16x4*)(o + 2 * EDIM) = L;
}

// ---------------- fused prep (round-15, proven) ----------------
__global__ __launch_bounds__(256) void k_prep(
        const float* __restrict__ x, const float* __restrict__ W,
        unsigned short* __restrict__ Xe, unsigned short* __restrict__ We,
        float* __restrict__ Z, float* __restrict__ c2,
        unsigned long long* __restrict__ keys, int* __restrict__ cnt) {
    const int bid = blockIdx.x, tid = threadIdx.x;
    if (bid < PREP_RN) {
#pragma clang fp contract(off)
        const int wave = tid >> 6, half = (tid >> 5) & 1, l32 = tid & 31;
        const int g = bid * 8 + wave * 2 + half;
        const float* src; float* dst; int gi;
        if (g < NROWS) { src = x + (size_t)g * EDIM; dst = Z; gi = g; }
        else { src = W + (size_t)(g - NROWS) * EDIM; dst = c2; gi = g - NROWS; }
        const int b = l32 >> 3, j = l32 & 7;
        const float* q = src + b * 128 + j;
        float v = q[0];
        float r = v * v;
        for (int i = 1; i < 16; ++i) { v = q[i * 8]; r = r + v * v; }
        r = r + __shfl_xor(r, 1, 64);
        r = r + __shfl_xor(r, 2, 64);
        r = r + __shfl_xor(r, 4, 64);    // = S_b, numpy pairing
        r = r + __shfl_xor(r, 8, 64);
        r = r + __shfl_xor(r, 16, 64);   // = (S0+S1)+(S2+S3)
        if (l32 == 0) dst[gi] = r;
    } else if (bid < PREP_SX) {
        split_group(x, Xe, (bid - PREP_RN) * 256 + tid);
    } else if (bid < PREP_SW) {
        split_group(W, We, (bid - PREP_SX) * 256 + tid);
    } else if (bid < PREP_KEYS) {
        keys[(bid - PREP_SW) * 256 + tid] = ~0ull;
    } else {
        if (tid < NTILE) cnt[tid] = 0;
    }
}

// ---------------- shared MFMA helpers ----------------
__device__ __forceinline__ void gld16(const void* g, void* l) {
    __builtin_amdgcn_global_load_lds((const __attribute__((address_space(1))) void*)g,
                                     (__attribute__((address_space(3))) void*)l, 16, 0, 0);
}

#define GBM 128
#define GBN 128
#define GBK 64

// ---------------- pass A: hi-GEMM, swapped orientation (round-10) ---------
__global__ __launch_bounds__(256) void k_argmin_hi(
        const unsigned short* __restrict__ Xe, const unsigned short* __restrict__ We,
        const float* __restrict__ c2, unsigned* __restrict__ tmin) {
    __shared__ __align__(16) unsigned short At[GBM * GBK];   // x rows
    __shared__ __align__(16) unsigned short Bt[GBN * GBK];   // code rows
    __shared__ unsigned smin[GBM];
    __shared__ float cs[GBN];                                // 4 + c2

    const int tid = threadIdx.x;
    const int lane = tid & 63, wid = tid >> 6;
    const int wr = wid >> 1, wc = wid & 1;

    const int bid = blockIdx.x;
    const int swz = (bid & 7) * 1024 + (bid >> 3);   // 8192 % 8 == 0, bijective
    const int rowtile = swz & 127, codetile = swz >> 7;
    const int row0 = rowtile * GBM, code0 = codetile * GBN;

    if (tid < GBM) smin[tid] = 0xFFFFFFFFu;
    if (tid < GBN) cs[tid] = 4.0f + c2[code0 + tid];

    f32x16 acc[2][2];
#pragma unroll
    for (int i = 0; i < 2; ++i)
#pragma unroll
        for (int j = 0; j < 2; ++j)
#pragma unroll
            for (int r = 0; r < 16; ++r) acc[i][j][r] = 0.0f;

    size_t ga[4], gb[4];
#pragma unroll
    for (int i = 0; i < 4; ++i) {
        int chunk = i * 256 + tid;
        int row   = chunk >> 3;
        int kcs   = (chunk & 7) ^ (row & 7);
        ga[i] = (size_t)(row0 + row) * K3 + kcs * 8;
        gb[i] = (size_t)(code0 + row) * K3 + kcs * 8;
    }

    const int cb0 = wr * 64 + (lane & 31);   // code row (M side)
    const int xa0 = wc * 64 + (lane & 31);   // x row (N side)
    const int kh  = lane >> 5;
    const int sb  = cb0 & 7, sa = xa0 & 7;

    for (int kt = 0; kt < EDIM / GBK; ++kt) {
        const size_t ko = (size_t)kt * GBK;
#pragma unroll
        for (int i = 0; i < 4; ++i) {
            gld16(Xe + ga[i] + ko, (char*)At + i * 4096 + wid * 1024);
            gld16(We + gb[i] + ko, (char*)Bt + i * 4096 + wid * 1024);
        }
        __syncthreads();
#pragma unroll
        for (int ks = 0; ks < 4; ++ks) {
            const int ch = ks * 2 + kh;
            short8 c0 = *(const short8*)((const char*)Bt + cb0 * 128        + ((ch ^ sb) * 16));
            short8 c1 = *(const short8*)((const char*)Bt + (cb0 + 32) * 128 + ((ch ^ sb) * 16));
            short8 x0 = *(const short8*)((const char*)At + xa0 * 128        + ((ch ^ sa) * 16));
            short8 x1 = *(const short8*)((const char*)At + (xa0 + 32) * 128 + ((ch ^ sa) * 16));
            acc[0][0] = __builtin_amdgcn_mfma_f32_32x32x16_bf16(c0, x0, acc[0][0], 0, 0, 0);
            acc[0][1] = __builtin_amdgcn_mfma_f32_32x32x16_bf16(c0, x1, acc[0][1], 0, 0, 0);
            acc[1][0] = __builtin_amdgcn_mfma_f32_32x32x16_bf16(c1, x0, acc[1][0], 0, 0, 0);
            acc[1][1] = __builtin_amdgcn_mfma_f32_32x32x16_bf16(c1, x1, acc[1][1], 0, 0, 0);
        }
        __syncthreads();
    }

    const int kh4 = kh * 4;
#pragma unroll
    for (int nj = 0; nj < 2; ++nj) {
        float dmin = 3.4e38f;
#pragma unroll
        for (int mi = 0; mi < 2; ++mi) {
#pragma unroll
            for (int q = 0; q < 4; ++q) {
                const float4 cq = *(const float4*)&cs[wr * 64 + mi * 32 + q * 8 + kh4];
                dmin = fminf(dmin, fmaf(-2.0f, acc[mi][nj][q * 4 + 0], cq.x));
                dmin = fminf(dmin, fmaf(-2.0f, acc[mi][nj][q * 4 + 1], cq.y));
                dmin = fminf(dmin, fmaf(-2.0f, acc[mi][nj][q * 4 + 2], cq.z));
                dmin = fminf(dmin, fmaf(-2.0f, acc[mi][nj][q * 4 + 3], cq.w));
            }
        }
        const int xr = wc * 64 + nj * 32 + (lane & 31);
        atomicMin(&smin[xr], __float_as_uint(dmin));
    }
    __syncthreads();
    if (tid < GBM) tmin[codetile * NROWS + row0 + tid] = smin[tid];
}

// ---------------- pass B: candidate tile selection ----------------
__global__ __launch_bounds__(256) void k_select(
        const unsigned* __restrict__ tmin, const float* __restrict__ Z,
        int* __restrict__ cnt, int* __restrict__ list) {
    const int row = blockIdx.x * 256 + threadIdx.x;
    unsigned mn = 0xFFFFFFFFu;
    for (int t = 0; t < NTILE; ++t) {
        unsigned v = tmin[t * NROWS + row];
        if (v < mn) mn = v;
    }
    const float margin = 4.35e-5f * sqrtf(Z[row]) + 1.7e-4f;
    const float thr = __uint_as_float(mn) + margin;
    for (int t = 0; t < NTILE; ++t) {
        if (__uint_as_float(tmin[t * NROWS + row]) <= thr) {
            int p = atomicAdd(&cnt[t], 1);
            list[t * NROWS + p] = row;
        }
    }
}

// ---------------- pass C: exact 6-split MFMA rescore, RK=128 steps --------
// Same geometry/orientation as round-10/15 (128 rows x 128 codes x K=3072),
// but K-step widened 64->128: 24 staging steps instead of 48. MFMA sequence
// (ch = 0..15 ascending per (bt,kc2)) is IDENTICAL to the (kc,ks) order of
// the proven kernel -> bitwise-identical distances. Swizzle mask widened
// 7->15 consistently on pre-swizzled source + read side (dest stays linear).
// LDS 65.5 KB -> 2 blocks/CU (not binding: ~1.3 busy blocks/CU).
#define RK 128
__global__ __launch_bounds__(256) void k_rescore_mfma(
        const unsigned short* __restrict__ Xe, const unsigned short* __restrict__ We,
        const float* __restrict__ Z, const float* __restrict__ c2,
        const int* __restrict__ cnt, const int* __restrict__ list,
        unsigned long long* __restrict__ keys) {
    __shared__ __align__(16) unsigned short At[GBM * RK];    // 32 KB
    __shared__ __align__(16) unsigned short Bt[GBN * RK];    // 32 KB
    __shared__ int rl_s[GBM];
    __shared__ float Zs[GBM];
    __shared__ float cs2[GBN];

    const int tile = blockIdx.x;
    const int n = cnt[tile];
    if (n == 0) return;
    const int* rows = list + tile * NROWS;
    const int tid = threadIdx.x;
    const int lane = tid & 63, wid = tid >> 6;
    const int wr = wid >> 1, wc = wid & 1;
    const int code0 = tile * 128;

    if (tid < GBN) cs2[tid] = c2[code0 + tid];

    const int cb0 = wr * 64 + (lane & 31);
    const int xa0 = wc * 64 + (lane & 31);
    const int kh  = lane >> 5;
    const int kh4 = kh * 4;
    const int sb  = cb0 & 15, sa = xa0 & 15;

    // staging maps: 2048 chunks of 16B per matrix per step, 8 loads/thread
    size_t boff[8];
    int arow8[8], akcs8[8];
#pragma unroll
    for (int i = 0; i < 8; ++i) {
        int chunk = i * 256 + tid;
        int row   = chunk >> 4;              // 16 chunks per row
        int kcs   = (chunk & 15) ^ (row & 15);
        arow8[i] = row; akcs8[i] = kcs;
        boff[i] = (size_t)(code0 + row) * K3 + kcs * 8;
    }

    for (int chk = (int)blockIdx.y; chk * GBM < n; chk += 16) {
        __syncthreads();
        if (tid < GBM) {
            int ri = chk * GBM + tid;
            int r = rows[ri < n ? ri : 0];
            rl_s[tid] = r;
            Zs[tid] = Z[r];
        }
        __syncthreads();

        size_t aoff[8];
#pragma unroll
        for (int i = 0; i < 8; ++i)
            aoff[i] = (size_t)rl_s[arow8[i]] * K3 + akcs8[i] * 8;

        f32x16 acc[2][2];
#pragma unroll
        for (int i = 0; i < 2; ++i)
#pragma unroll
            for (int j = 0; j < 2; ++j)
#pragma unroll
                for (int r = 0; r < 16; ++r) acc[i][j][r] = 0.0f;

#pragma unroll
        for (int bt = 0; bt < 6; ++bt) {
            const int ao = (bt == 1 || bt == 2) ? EDIM : (bt == 4 ? 2 * EDIM : 0);
            const int bo = (bt == 0 || bt == 2) ? EDIM : (bt == 3 ? 2 * EDIM : 0);
            for (int kc2 = 0; kc2 < 4; ++kc2) {
                const int ko = ao + kc2 * RK;
                const int kob = bo + kc2 * RK;
#pragma unroll
                for (int i = 0; i < 8; ++i) {
                    gld16(Xe + aoff[i] + ko,  (char*)At + i * 4096 + wid * 1024);
                    gld16(We + boff[i] + kob, (char*)Bt + i * 4096 + wid * 1024);
                }
                __syncthreads();
#pragma unroll
                for (int ks2 = 0; ks2 < 8; ++ks2) {
                    const int ch = ks2 * 2 + kh;                 // 0..15
                    short8 cf0 = *(const short8*)((const char*)Bt + cb0 * 256        + ((ch ^ sb) * 16));
                    short8 cf1 = *(const short8*)((const char*)Bt + (cb0 + 32) * 256 + ((ch ^ sb) * 16));
                    short8 xf0 = *(const short8*)((const char*)At + xa0 * 256        + ((ch ^ sa) * 16));
                    short8 xf1 = *(const short8*)((const char*)At + (xa0 + 32) * 256 + ((ch ^ sa) * 16));
                    acc[0][0] = __builtin_amdgcn_mfma_f32_32x32x16_bf16(cf0, xf0, acc[0][0], 0, 0, 0);
                    acc[0][1] = __builtin_amdgcn_mfma_f32_32x32x16_bf16(cf0, xf1, acc[0][1], 0, 0, 0);
                    acc[1][0] = __builtin_amdgcn_mfma_f32_32x32x16_bf16(cf1, xf0, acc[1][0], 0, 0, 0);
                    acc[1][1] = __builtin_amdgcn_mfma_f32_32x32x16_bf16(cf1, xf1, acc[1][1], 0, 0, 0);
                }
                __syncthreads();
            }
        }

        // epilogue: exact d = (Z + c2) - 2*m, per-lane (d,j) argmin
#pragma unroll
        for (int nj = 0; nj < 2; ++nj) {
            const int xr = wc * 64 + nj * 32 + (lane & 31);
            const float Zr = Zs[xr];
            float dm = 3.4e38f; int jm = 0;
#pragma unroll
            for (int mi = 0; mi < 2; ++mi) {
#pragma unroll
                for (int q = 0; q < 4; ++q) {
                    const float4 cq = *(const float4*)&cs2[wr * 64 + mi * 32 + q * 8 + kh4];
                    const int jb = code0 + wr * 64 + mi * 32 + q * 8 + kh4;
                    { const float d = (Zr + cq.x) - 2.0f * acc[mi][nj][q * 4 + 0];
                      if (d < dm) { dm = d; jm = jb + 0; } }
                    { const float d = (Zr + cq.y) - 2.0f * acc[mi][nj][q * 4 + 1];
                      if (d < dm) { dm = d; jm = jb + 1; } }
                    { const float d = (Zr + cq.z) - 2.0f * acc[mi][nj][q * 4 + 2];
                      if (d < dm) { dm = d; jm = jb + 2; } }
                    { const float d = (Zr + cq.w) - 2.0f * acc[mi][nj][q * 4 + 3];
                      if (d < dm) { dm = d; jm = jb + 3; } }
                }
            }
            const unsigned long long k =
                (((unsigned long long)__float_as_uint(dm)) << 13) | (unsigned)jm;
            atomicMin(&keys[rl_s[xr]], k);
        }
    }
}

// ---------------- gather / loss partials / finalize ----------------
__global__ __launch_bounds__(256) void k_gather(
        const float* __restrict__ x, const float* __restrict__ W,
        const unsigned long long* __restrict__ keys,
        float* __restrict__ out, double* __restrict__ part) {
    const int tid = threadIdx.x;
    const int row = blockIdx.x * 8 + (tid >> 5);
    const int c = tid & 31;
    const int idx = (int)(keys[row] & 0x1FFFull);

    const float* wrow = W + (size_t)idx * EDIM;
    const float* xrow = x + (size_t)row * EDIM;
    float* orow = out + (size_t)row * EDIM;

    double lsum = 0.0;
#pragma unroll
    for (int v = 0; v < 4; ++v) {
        const int d = c * 4 + v * 128;
        float4 xv = *(const float4*)(xrow + d);
        float4 wv = *(const float4*)(wrow + d);
        float t0 = wv.x - xv.x, t1 = wv.y - xv.y, t2 = wv.z - xv.z, t3 = wv.w - xv.w;
        float4 ov = { xv.x + t0, xv.y + t1, xv.z + t2, xv.w + t3 };
        *(float4*)(orow + d) = ov;
        lsum += (double)t0 * t0 + (double)t1 * t1 + (double)t2 * t2 + (double)t3 * t3;
    }
    if (c == 0) out[XQSZ + 1 + row] = (float)idx;

#pragma unroll
    for (int off = 32; off > 0; off >>= 1) lsum += __shfl_down(lsum, off, 64);
    __shared__ double pb[4];
    if ((tid & 63) == 0) pb[tid >> 6] = lsum;
    __syncthreads();
    if (tid == 0) part[blockIdx.x] = pb[0] + pb[1] + pb[2] + pb[3];
}

__global__ __launch_bounds__(256) void k_finalize(float* __restrict__ out,
        const double* __restrict__ part) {
    const int tid = threadIdx.x;
    double s = 0.0;
    for (int i = tid; i < 2048; i += 256) s += part[i];
#pragma unroll
    for (int off = 32; off > 0; off >>= 1) s += __shfl_down(s, off, 64);
    __shared__ double pb[4];
    if ((tid & 63) == 0) pb[tid >> 6] = s;
    __syncthreads();
    if (tid == 0) out[XQSZ] = (float)(0.25 * (pb[0] + pb[1] + pb[2] + pb[3]) / (double)XQSZ);
}

extern "C" void kernel_launch(void* const* d_in, const int* in_sizes, int n_in,
                              void* d_out, int out_size, void* d_ws, size_t ws_size,
                              hipStream_t stream) {
    const float* x = (const float*)d_in[0];
    const float* W = (const float*)d_in[3];
    float* out = (float*)d_out;
    char* ws = (char*)d_ws;

    double* part = (double*)(ws + OFF_PART);
    float* Z    = (float*)(ws + OFF_Z);
    float* c2   = (float*)(ws + OFF_C2);
    unsigned long long* keys = (unsigned long long*)(ws + OFF_KEYS);
    unsigned* tmin = (unsigned*)(ws + OFF_TMIN);
    int* cnt  = (int*)(ws + OFF_CNT);
    int* list = (int*)(ws + OFF_LIST);
    unsigned short* Xe = (unsigned short*)(ws + OFF_XE);
    unsigned short* We = (unsigned short*)(ws + OFF_WE);

    k_prep<<<PREP_ALL, 256, 0, stream>>>(x, W, Xe, We, Z, c2, keys, cnt);
    k_argmin_hi<<<(NROWS / GBM) * (NE / GBN), 256, 0, stream>>>(Xe, We, c2, tmin);
    k_select<<<NROWS / 256, 256, 0, stream>>>(tmin, Z, cnt, list);
    k_rescore_mfma<<<dim3(NTILE, 16), 256, 0, stream>>>(Xe, We, Z, c2, cnt, list, keys);
    k_gather<<<NROWS / 8, 256, 0, stream>>>(x, W, keys, out, part);
    k_finalize<<<1, 256, 0, stream>>>(out, part);
}

// Round 17
// 493.233 us; speedup vs baseline: 1.0922x; 1.0922x over previous
//
#include <hip/hip_runtime.h>
#include <cstdint>
#include <cstddef>

#define EDIM  512
#define NROWS 16384
#define NE    8192
#define XQSZ  (NROWS * EDIM)   // 8388608
#define NTILE 64               // 8192 codes / 128 per tile
#define K3    1536             // 3-block split: [hi, mid, lo]

// workspace byte offsets
#define OFF_PART  0                          // 2048 doubles
#define OFF_Z     16384
#define OFF_C2    81920
#define OFF_KEYS  114688
#define OFF_TMIN  245760                     // NROWS*NTILE*4 = 4 MB
#define OFF_CNT   4440064
#define OFF_LIST  4441088                    // NROWS*NTILE*4 = 4 MB
#define OFF_XE    8635392                    // NROWS*K3*2 = 48 MB
#define OFF_WE    58967040                   // NE*K3*2 = 24 MB (end ~84 MB)

// k_prep grid regions
#define PREP_RN   3072                       // rownorm: 2 rows/wave, 8 rows/block
#define PREP_SX   (PREP_RN + 8192)           // x split
#define PREP_SW   (PREP_SX + 4096)           // W split
#define PREP_KEYS (PREP_SW + 64)             // keys init
#define PREP_ALL  (PREP_KEYS + 1)            // + cnt zero

typedef __attribute__((ext_vector_type(8)))  short          short8;
typedef __attribute__((ext_vector_type(16))) float          f32x16;
typedef __attribute__((ext_vector_type(4)))  unsigned short u16x4;

// ---------------- bf16 split helpers ----------------
__device__ __forceinline__ unsigned short f2bf(float f) {
    unsigned u = __float_as_uint(f);
    return (unsigned short)((u + 0x7FFFu + ((u >> 16) & 1u)) >> 16);
}
__device__ __forceinline__ float bf2f(unsigned short h) {
    return __uint_as_float(((unsigned)h) << 16);
}

__device__ __forceinline__ void split_group(const float* __restrict__ in,
        unsigned short* __restrict__ outp, int e) {
    int row = e >> 7;               // 128 float4-groups per row
    int d0  = (e & 127) << 2;
    float4 v = *(const float4*)(in + (size_t)row * EDIM + d0);
    float vv[4] = {v.x, v.y, v.z, v.w};
    u16x4 H, M, L;
#pragma unroll
    for (int i = 0; i < 4; ++i) {
        float f = vv[i];
        unsigned short h = f2bf(f);
        float r1 = f - bf2f(h);          // exact
        unsigned short m = f2bf(r1);
        float r2 = r1 - bf2f(m);         // exact
        L[i] = f2bf(r2); H[i] = h; M[i] = m;
    }
    unsigned short* o = outp + (size_t)row * K3 + d0;
    *(u16x4*)(o) = H; *(u16x4*)(o + EDIM) = M; *(u16x4*)(o + 2 * EDIM) = L;
}

// ---------------- fused prep (round-15, proven) ----------------
__global__ __launch_bounds__(256) void k_prep(
        const float* __restrict__ x, const float* __restrict__ W,
        unsigned short* __restrict__ Xe, unsigned short* __restrict__ We,
        float* __restrict__ Z, float* __restrict__ c2,
        unsigned long long* __restrict__ keys, int* __restrict__ cnt) {
    const int bid = blockIdx.x, tid = threadIdx.x;
    if (bid < PREP_RN) {
#pragma clang fp contract(off)
        const int wave = tid >> 6, half = (tid >> 5) & 1, l32 = tid & 31;
        const int g = bid * 8 + wave * 2 + half;
        const float* src; float* dst; int gi;
        if (g < NROWS) { src = x + (size_t)g * EDIM; dst = Z; gi = g; }
        else { src = W + (size_t)(g - NROWS) * EDIM; dst = c2; gi = g - NROWS; }
        const int b = l32 >> 3, j = l32 & 7;
        const float* q = src + b * 128 + j;
        float v = q[0];
        float r = v * v;
        for (int i = 1; i < 16; ++i) { v = q[i * 8]; r = r + v * v; }
        r = r + __shfl_xor(r, 1, 64);
        r = r + __shfl_xor(r, 2, 64);
        r = r + __shfl_xor(r, 4, 64);    // = S_b, numpy pairing
        r = r + __shfl_xor(r, 8, 64);
        r = r + __shfl_xor(r, 16, 64);   // = (S0+S1)+(S2+S3)
        if (l32 == 0) dst[gi] = r;
    } else if (bid < PREP_SX) {
        split_group(x, Xe, (bid - PREP_RN) * 256 + tid);
    } else if (bid < PREP_SW) {
        split_group(W, We, (bid - PREP_SX) * 256 + tid);
    } else if (bid < PREP_KEYS) {
        keys[(bid - PREP_SW) * 256 + tid] = ~0ull;
    } else {
        if (tid < NTILE) cnt[tid] = 0;
    }
}

// ---------------- shared MFMA helpers ----------------
__device__ __forceinline__ void gld16(const void* g, void* l) {
    __builtin_amdgcn_global_load_lds((const __attribute__((address_space(1))) void*)g,
                                     (__attribute__((address_space(3))) void*)l, 16, 0, 0);
}

#define GBM 128
#define GBN 128
#define GBK 64

// ---------------- pass A: hi-GEMM, swapped orientation (round-10) ---------
__global__ __launch_bounds__(256) void k_argmin_hi(
        const unsigned short* __restrict__ Xe, const unsigned short* __restrict__ We,
        const float* __restrict__ c2, unsigned* __restrict__ tmin) {
    __shared__ __align__(16) unsigned short At[GBM * GBK];   // x rows
    __shared__ __align__(16) unsigned short Bt[GBN * GBK];   // code rows
    __shared__ unsigned smin[GBM];
    __shared__ float cs[GBN];                                // 4 + c2

    const int tid = threadIdx.x;
    const int lane = tid & 63, wid = tid >> 6;
    const int wr = wid >> 1, wc = wid & 1;

    const int bid = blockIdx.x;
    const int swz = (bid & 7) * 1024 + (bid >> 3);   // 8192 % 8 == 0, bijective
    const int rowtile = swz & 127, codetile = swz >> 7;
    const int row0 = rowtile * GBM, code0 = codetile * GBN;

    if (tid < GBM) smin[tid] = 0xFFFFFFFFu;
    if (tid < GBN) cs[tid] = 4.0f + c2[code0 + tid];

    f32x16 acc[2][2];
#pragma unroll
    for (int i = 0; i < 2; ++i)
#pragma unroll
        for (int j = 0; j < 2; ++j)
#pragma unroll
            for (int r = 0; r < 16; ++r) acc[i][j][r] = 0.0f;

    size_t ga[4], gb[4];
#pragma unroll
    for (int i = 0; i < 4; ++i) {
        int chunk = i * 256 + tid;
        int row   = chunk >> 3;
        int kcs   = (chunk & 7) ^ (row & 7);
        ga[i] = (size_t)(row0 + row) * K3 + kcs * 8;
        gb[i] = (size_t)(code0 + row) * K3 + kcs * 8;
    }

    const int cb0 = wr * 64 + (lane & 31);   // code row (M side)
    const int xa0 = wc * 64 + (lane & 31);   // x row (N side)
    const int kh  = lane >> 5;
    const int sb  = cb0 & 7, sa = xa0 & 7;

    for (int kt = 0; kt < EDIM / GBK; ++kt) {
        const size_t ko = (size_t)kt * GBK;
#pragma unroll
        for (int i = 0; i < 4; ++i) {
            gld16(Xe + ga[i] + ko, (char*)At + i * 4096 + wid * 1024);
            gld16(We + gb[i] + ko, (char*)Bt + i * 4096 + wid * 1024);
        }
        __syncthreads();
#pragma unroll
        for (int ks = 0; ks < 4; ++ks) {
            const int ch = ks * 2 + kh;
            short8 c0 = *(const short8*)((const char*)Bt + cb0 * 128        + ((ch ^ sb) * 16));
            short8 c1 = *(const short8*)((const char*)Bt + (cb0 + 32) * 128 + ((ch ^ sb) * 16));
            short8 x0 = *(const short8*)((const char*)At + xa0 * 128        + ((ch ^ sa) * 16));
            short8 x1 = *(const short8*)((const char*)At + (xa0 + 32) * 128 + ((ch ^ sa) * 16));
            acc[0][0] = __builtin_amdgcn_mfma_f32_32x32x16_bf16(c0, x0, acc[0][0], 0, 0, 0);
            acc[0][1] = __builtin_amdgcn_mfma_f32_32x32x16_bf16(c0, x1, acc[0][1], 0, 0, 0);
            acc[1][0] = __builtin_amdgcn_mfma_f32_32x32x16_bf16(c1, x0, acc[1][0], 0, 0, 0);
            acc[1][1] = __builtin_amdgcn_mfma_f32_32x32x16_bf16(c1, x1, acc[1][1], 0, 0, 0);
        }
        __syncthreads();
    }

    const int kh4 = kh * 4;
#pragma unroll
    for (int nj = 0; nj < 2; ++nj) {
        float dmin = 3.4e38f;
#pragma unroll
        for (int mi = 0; mi < 2; ++mi) {
#pragma unroll
            for (int q = 0; q < 4; ++q) {
                const float4 cq = *(const float4*)&cs[wr * 64 + mi * 32 + q * 8 + kh4];
                dmin = fminf(dmin, fmaf(-2.0f, acc[mi][nj][q * 4 + 0], cq.x));
                dmin = fminf(dmin, fmaf(-2.0f, acc[mi][nj][q * 4 + 1], cq.y));
                dmin = fminf(dmin, fmaf(-2.0f, acc[mi][nj][q * 4 + 2], cq.z));
                dmin = fminf(dmin, fmaf(-2.0f, acc[mi][nj][q * 4 + 3], cq.w));
            }
        }
        const int xr = wc * 64 + nj * 32 + (lane & 31);
        atomicMin(&smin[xr], __float_as_uint(dmin));
    }
    __syncthreads();
    if (tid < GBM) tmin[codetile * NROWS + row0 + tid] = smin[tid];
}

// ---------------- pass B: candidate tile selection ----------------
__global__ __launch_bounds__(256) void k_select(
        const unsigned* __restrict__ tmin, const float* __restrict__ Z,
        int* __restrict__ cnt, int* __restrict__ list) {
    const int row = blockIdx.x * 256 + threadIdx.x;
    unsigned mn = 0xFFFFFFFFu;
    for (int t = 0; t < NTILE; ++t) {
        unsigned v = tmin[t * NROWS + row];
        if (v < mn) mn = v;
    }
    const float margin = 4.35e-5f * sqrtf(Z[row]) + 1.7e-4f;
    const float thr = __uint_as_float(mn) + margin;
    for (int t = 0; t < NTILE; ++t) {
        if (__uint_as_float(tmin[t * NROWS + row]) <= thr) {
            int p = atomicAdd(&cnt[t], 1);
            list[t * NROWS + p] = row;
        }
    }
}

// ---------------- pass C: exact 6-split MFMA rescore (round-10, proven) ---
// 128 rows x 128 codes x K=3072 per chunk, GBK=64 steps. Frozen: rounds
// 11 (small chunks), 12 (counted-vmcnt dbuf), 13 (register-direct), 16
// (RK=128) all regressed vs this structure.
__global__ __launch_bounds__(256) void k_rescore_mfma(
        const unsigned short* __restrict__ Xe, const unsigned short* __restrict__ We,
        const float* __restrict__ Z, const float* __restrict__ c2,
        const int* __restrict__ cnt, const int* __restrict__ list,
        unsigned long long* __restrict__ keys) {
    __shared__ __align__(16) unsigned short At[GBM * GBK];
    __shared__ __align__(16) unsigned short Bt[GBN * GBK];
    __shared__ int rl_s[GBM];
    __shared__ float Zs[GBM];
    __shared__ float cs2[GBN];

    const int tile = blockIdx.x;
    const int n = cnt[tile];
    if (n == 0) return;
    const int* rows = list + tile * NROWS;
    const int tid = threadIdx.x;
    const int lane = tid & 63, wid = tid >> 6;
    const int wr = wid >> 1, wc = wid & 1;
    const int code0 = tile * 128;

    if (tid < GBN) cs2[tid] = c2[code0 + tid];

    const int cb0 = wr * 64 + (lane & 31);
    const int xa0 = wc * 64 + (lane & 31);
    const int kh  = lane >> 5;
    const int kh4 = kh * 4;
    const int sb  = cb0 & 7, sa = xa0 & 7;

    size_t boff[4];
    int arow4[4], akcs4[4];
#pragma unroll
    for (int i = 0; i < 4; ++i) {
        int chunk = i * 256 + tid;
        int row   = chunk >> 3;
        int kcs   = (chunk & 7) ^ (row & 7);
        arow4[i] = row; akcs4[i] = kcs;
        boff[i] = (size_t)(code0 + row) * K3 + kcs * 8;
    }

    for (int chk = (int)blockIdx.y; chk * GBM < n; chk += 16) {
        __syncthreads();
        if (tid < GBM) {
            int ri = chk * GBM + tid;
            int r = rows[ri < n ? ri : 0];
            rl_s[tid] = r;
            Zs[tid] = Z[r];
        }
        __syncthreads();

        size_t aoff[4];
#pragma unroll
        for (int i = 0; i < 4; ++i)
            aoff[i] = (size_t)rl_s[arow4[i]] * K3 + akcs4[i] * 8;

        f32x16 acc[2][2];
#pragma unroll
        for (int i = 0; i < 2; ++i)
#pragma unroll
            for (int j = 0; j < 2; ++j)
#pragma unroll
                for (int r = 0; r < 16; ++r) acc[i][j][r] = 0.0f;

#pragma unroll
        for (int bt = 0; bt < 6; ++bt) {
            const int ao = (bt == 1 || bt == 2) ? EDIM : (bt == 4 ? 2 * EDIM : 0);
            const int bo = (bt == 0 || bt == 2) ? EDIM : (bt == 3 ? 2 * EDIM : 0);
            for (int kc = 0; kc < 8; ++kc) {
                const int ko = ao + kc * GBK;
                const int kob = bo + kc * GBK;
#pragma unroll
                for (int i = 0; i < 4; ++i) {
                    gld16(Xe + aoff[i] + ko,  (char*)At + i * 4096 + wid * 1024);
                    gld16(We + boff[i] + kob, (char*)Bt + i * 4096 + wid * 1024);
                }
                __syncthreads();
#pragma unroll
                for (int ks = 0; ks < 4; ++ks) {
                    const int ch = ks * 2 + kh;
                    short8 cf0 = *(const short8*)((const char*)Bt + cb0 * 128        + ((ch ^ sb) * 16));
                    short8 cf1 = *(const short8*)((const char*)Bt + (cb0 + 32) * 128 + ((ch ^ sb) * 16));
                    short8 xf0 = *(const short8*)((const char*)At + xa0 * 128        + ((ch ^ sa) * 16));
                    short8 xf1 = *(const short8*)((const char*)At + (xa0 + 32) * 128 + ((ch ^ sa) * 16));
                    acc[0][0] = __builtin_amdgcn_mfma_f32_32x32x16_bf16(cf0, xf0, acc[0][0], 0, 0, 0);
                    acc[0][1] = __builtin_amdgcn_mfma_f32_32x32x16_bf16(cf0, xf1, acc[0][1], 0, 0, 0);
                    acc[1][0] = __builtin_amdgcn_mfma_f32_32x32x16_bf16(cf1, xf0, acc[1][0], 0, 0, 0);
                    acc[1][1] = __builtin_amdgcn_mfma_f32_32x32x16_bf16(cf1, xf1, acc[1][1], 0, 0, 0);
                }
                __syncthreads();
            }
        }

#pragma unroll
        for (int nj = 0; nj < 2; ++nj) {
            const int xr = wc * 64 + nj * 32 + (lane & 31);
            const float Zr = Zs[xr];
            float dm = 3.4e38f; int jm = 0;
#pragma unroll
            for (int mi = 0; mi < 2; ++mi) {
#pragma unroll
                for (int q = 0; q < 4; ++q) {
                    const float4 cq = *(const float4*)&cs2[wr * 64 + mi * 32 + q * 8 + kh4];
                    const int jb = code0 + wr * 64 + mi * 32 + q * 8 + kh4;
                    { const float d = (Zr + cq.x) - 2.0f * acc[mi][nj][q * 4 + 0];
                      if (d < dm) { dm = d; jm = jb + 0; } }
                    { const float d = (Zr + cq.y) - 2.0f * acc[mi][nj][q * 4 + 1];
                      if (d < dm) { dm = d; jm = jb + 1; } }
                    { const float d = (Zr + cq.z) - 2.0f * acc[mi][nj][q * 4 + 2];
                      if (d < dm) { dm = d; jm = jb + 2; } }
                    { const float d = (Zr + cq.w) - 2.0f * acc[mi][nj][q * 4 + 3];
                      if (d < dm) { dm = d; jm = jb + 3; } }
                }
            }
            const unsigned long long k =
                (((unsigned long long)__float_as_uint(dm)) << 13) | (unsigned)jm;
            atomicMin(&keys[rl_s[xr]], k);
        }
    }
}

// ---------------- gather / loss partials / finalize ----------------
__global__ __launch_bounds__(256) void k_gather(
        const float* __restrict__ x, const float* __restrict__ W,
        const unsigned long long* __restrict__ keys,
        float* __restrict__ out, double* __restrict__ part) {
    const int tid = threadIdx.x;
    const int row = blockIdx.x * 8 + (tid >> 5);
    const int c = tid & 31;
    const int idx = (int)(keys[row] & 0x1FFFull);

    const float* wrow = W + (size_t)idx * EDIM;
    const float* xrow = x + (size_t)row * EDIM;
    float* orow = out + (size_t)row * EDIM;

    double lsum = 0.0;
#pragma unroll
    for (int v = 0; v < 4; ++v) {
        const int d = c * 4 + v * 128;
        float4 xv = *(const float4*)(xrow + d);
        float4 wv = *(const float4*)(wrow + d);
        float t0 = wv.x - xv.x, t1 = wv.y - xv.y, t2 = wv.z - xv.z, t3 = wv.w - xv.w;
        float4 ov = { xv.x + t0, xv.y + t1, xv.z + t2, xv.w + t3 };
        *(float4*)(orow + d) = ov;
        lsum += (double)t0 * t0 + (double)t1 * t1 + (double)t2 * t2 + (double)t3 * t3;
    }
    if (c == 0) out[XQSZ + 1 + row] = (float)idx;

#pragma unroll
    for (int off = 32; off > 0; off >>= 1) lsum += __shfl_down(lsum, off, 64);
    __shared__ double pb[4];
    if ((tid & 63) == 0) pb[tid >> 6] = lsum;
    __syncthreads();
    if (tid == 0) part[blockIdx.x] = pb[0] + pb[1] + pb[2] + pb[3];
}

__global__ __launch_bounds__(256) void k_finalize(float* __restrict__ out,
        const double* __restrict__ part) {
    const int tid = threadIdx.x;
    double s = 0.0;
    for (int i = tid; i < 2048; i += 256) s += part[i];
#pragma unroll
    for (int off = 32; off > 0; off >>= 1) s += __shfl_down(s, off, 64);
    __shared__ double pb[4];
    if ((tid & 63) == 0) pb[tid >> 6] = s;
    __syncthreads();
    if (tid == 0) out[XQSZ] = (float)(0.25 * (pb[0] + pb[1] + pb[2] + pb[3]) / (double)XQSZ);
}

extern "C" void kernel_launch(void* const* d_in, const int* in_sizes, int n_in,
                              void* d_out, int out_size, void* d_ws, size_t ws_size,
                              hipStream_t stream) {
    const float* x = (const float*)d_in[0];
    const float* W = (const float*)d_in[3];
    float* out = (float*)d_out;
    char* ws = (char*)d_ws;

    double* part = (double*)(ws + OFF_PART);
    float* Z    = (float*)(ws + OFF_Z);
    float* c2   = (float*)(ws + OFF_C2);
    unsigned long long* keys = (unsigned long long*)(ws + OFF_KEYS);
    unsigned* tmin = (unsigned*)(ws + OFF_TMIN);
    int* cnt  = (int*)(ws + OFF_CNT);
    int* list = (int*)(ws + OFF_LIST);
    unsigned short* Xe = (unsigned short*)(ws + OFF_XE);
    unsigned short* We = (unsigned short*)(ws + OFF_WE);

    k_prep<<<PREP_ALL, 256, 0, stream>>>(x, W, Xe, We, Z, c2, keys, cnt);
    k_argmin_hi<<<(NROWS / GBM) * (NE / GBN), 256, 0, stream>>>(Xe, We, c2, tmin);
    k_select<<<NROWS / 256, 256, 0, stream>>>(tmin, Z, cnt, list);
    k_rescore_mfma<<<dim3(NTILE, 16), 256, 0, stream>>>(Xe, We, Z, c2, cnt, list, keys);
    k_gather<<<NROWS / 8, 256, 0, stream>>>(x, W, keys, out, part);
    k_finalize<<<1, 256, 0, stream>>>(out, part);
}